// Round 5
// baseline (841.730 us; speedup 1.0000x reference)
//
#include <hip/hip_runtime.h>

static constexpr int B_    = 64;
static constexpr int N_    = 2048;
static constexpr int DI_   = 8;
static constexpr int O_    = 32;
static constexpr int P_    = 16;
static constexpr int OP_   = O_ * P_;      // 512
static constexpr int M_    = OP_ * B_;     // 32768 elements of s
static constexpr int CHUNK_ = 8;
static constexpr int NBLK_  = N_ / CHUNK_; // 256

__device__ __forceinline__ float dot8v(const float4& wa, const float4& wb,
                                       const float4& xa, const float4& xb) {
  float pr = wa.x * xa.x;
  pr = __builtin_fmaf(wa.y, xa.y, pr);
  pr = __builtin_fmaf(wa.z, xa.z, pr);
  pr = __builtin_fmaf(wa.w, xa.w, pr);
  pr = __builtin_fmaf(wb.x, xb.x, pr);
  pr = __builtin_fmaf(wb.y, xb.y, pr);
  pr = __builtin_fmaf(wb.z, xb.z, pr);
  pr = __builtin_fmaf(wb.w, xb.w, pr);
  return pr;
}

// MODE 0: iter0 (uniform rw; 1/32 folded into v_kernel). B only, sc=1.
// MODE 1: A (logits vs v_in) + softmax + B with register-carried preds.
// MODE 2: MODE1 + write normalized rw to rw_out (v_in = v0+v1 by linearity).
template <int MODE, bool ATOMIC>
__global__ __launch_bounds__(1024, 4)
void fused_pass(const float* __restrict__ x, const float* __restrict__ W,
                const float* __restrict__ v_in, float* __restrict__ s_out,
                float* __restrict__ rw_out) {
  __shared__ float Wl[2][O_ * P_ * DI_];     // 2 x 16 KB double-buffered W[n]
  __shared__ float x_lds[CHUNK_ * 8 * 65];   // [rem=(nn*8+i)][b], pad 65
  __shared__ float a_lds[O_ * B_];           // [o][b] logits for current nn
  __shared__ float mz[2][B_];                // m(b), 1/Z(b)
  const int tid  = threadIdx.x;
  const int lane = tid & 63;                  // lane == batch b
  const int wave = tid >> 6;                  // 0..15; wave owns o = 2w, 2w+1
  const int n0   = blockIdx.x * CHUNK_;
  const float4* Wg4 = (const float4*)W;       // W[n] = 1024 float4

  // prologue: issue W[n0] stage + x stage, one barrier
  float4 t0 = Wg4[(size_t)n0 * 1024 + tid];
  #pragma unroll
  for (int k = 0; k < 4; ++k) {
    int d = k * 1024 + tid;
    int b = d >> 6, rem = d & 63;
    x_lds[rem * 65 + b] = x[b * (N_ * DI_) + n0 * DI_ + rem];
  }
  ((float4*)&Wl[0][0])[tid] = t0;

  // v fragments for this wave's two o (32 VGPR)
  float4 va[2][4];
  if (MODE != 0) {
    #pragma unroll
    for (int oo = 0; oo < 2; ++oo) {
      const float4* vp = (const float4*)(v_in + (size_t)lane * OP_ + (wave * 2 + oo) * P_);
      #pragma unroll
      for (int q = 0; q < 4; ++q) va[oo][q] = vp[q];
    }
  }

  float4 sA[2][4];
  #pragma unroll
  for (int oo = 0; oo < 2; ++oo)
    #pragma unroll
    for (int q = 0; q < 4; ++q) sA[oo][q] = float4{0, 0, 0, 0};

  __syncthreads();

  #pragma unroll 1
  for (int nn = 0; nn < CHUNK_; ++nn) {
    const int cur = nn & 1, nxt = cur ^ 1;
    float4 wst;
    if (nn < CHUNK_ - 1) wst = Wg4[(size_t)(n0 + nn + 1) * 1024 + tid];  // prefetch

    float4 xa, xb;
    {
      const float* xp = &x_lds[nn * 8 * 65 + lane];
      xa.x = xp[0];   xa.y = xp[65];  xa.z = xp[130]; xa.w = xp[195];
      xb.x = xp[260]; xb.y = xp[325]; xb.z = xp[390]; xb.w = xp[455];
    }

    if (MODE != 0) {
      float pr[2][16];
      float ao[2];
      // ---- A: preds into regs, logits into a_lds ----
      #pragma unroll
      for (int oo = 0; oo < 2; ++oo) {
        const int o = wave * 2 + oo;
        const float4* wr = (const float4*)&Wl[cur][o * (P_ * DI_)];
        float acc = 0.0f;
        #pragma unroll
        for (int p = 0; p < P_; ++p) {
          float v = dot8v(wr[p * 2], wr[p * 2 + 1], xa, xb);
          pr[oo][p] = v;
          const float* vf = (const float*)&va[oo][p >> 2];
          acc = __builtin_fmaf(v, vf[p & 3], acc);
        }
        ao[oo] = acc;
        a_lds[o * B_ + lane] = acc;
      }
      __syncthreads();  // S1: a_lds complete

      if (wave == 0) {
        float m = -3.0e38f;
        #pragma unroll
        for (int o = 0; o < O_; ++o) m = fmaxf(m, a_lds[o * B_ + lane]);
        float Z = 0.0f;
        #pragma unroll
        for (int o = 0; o < O_; ++o) Z += __expf(a_lds[o * B_ + lane] - m);
        mz[0][lane] = m;
        mz[1][lane] = 1.0f / Z;
      }
      if (nn < CHUNK_ - 1) ((float4*)&Wl[nxt][0])[tid] = wst;  // stage next W
      __syncthreads();  // S2: mz + next W ready

      const float m  = mz[0][lane];
      const float rz = mz[1][lane];
      // ---- B: s += rw * preds (registers) ----
      #pragma unroll
      for (int oo = 0; oo < 2; ++oo) {
        const float rw = __expf(ao[oo] - m) * rz;
        #pragma unroll
        for (int q = 0; q < 4; ++q) {
          float* sf = (float*)&sA[oo][q];
          sf[0] = __builtin_fmaf(rw, pr[oo][q * 4 + 0], sf[0]);
          sf[1] = __builtin_fmaf(rw, pr[oo][q * 4 + 1], sf[1]);
          sf[2] = __builtin_fmaf(rw, pr[oo][q * 4 + 2], sf[2]);
          sf[3] = __builtin_fmaf(rw, pr[oo][q * 4 + 3], sf[3]);
        }
        if (MODE == 2) {
          // defer to pair store below via rw regs
          if (oo == 1) {
            const float rw0 = __expf(ao[0] - m) * rz;
            float2 t; t.x = rw0; t.y = rw;
            *(float2*)(rw_out + ((size_t)lane * N_ + (n0 + nn)) * O_ + wave * 2) = t;
          }
        }
      }
    } else {
      // ---- MODE0: B only with sc = 1 ----
      #pragma unroll
      for (int oo = 0; oo < 2; ++oo) {
        const int o = wave * 2 + oo;
        const float4* wr = (const float4*)&Wl[cur][o * (P_ * DI_)];
        #pragma unroll
        for (int q = 0; q < 4; ++q) {
          float* sf = (float*)&sA[oo][q];
          sf[0] += dot8v(wr[(q * 4 + 0) * 2], wr[(q * 4 + 0) * 2 + 1], xa, xb);
          sf[1] += dot8v(wr[(q * 4 + 1) * 2], wr[(q * 4 + 1) * 2 + 1], xa, xb);
          sf[2] += dot8v(wr[(q * 4 + 2) * 2], wr[(q * 4 + 2) * 2 + 1], xa, xb);
          sf[3] += dot8v(wr[(q * 4 + 3) * 2], wr[(q * 4 + 3) * 2 + 1], xa, xb);
        }
      }
      if (nn < CHUNK_ - 1) ((float4*)&Wl[nxt][0])[tid] = wst;
      __syncthreads();  // separates stage write from next read
    }
  }

  // ---- epilogue: s partial (or atomic) ----
  #pragma unroll
  for (int oo = 0; oo < 2; ++oo) {
    const int o = wave * 2 + oo;
    if (ATOMIC) {
      float* sp = s_out + (size_t)(o * P_) * B_ + lane;
      #pragma unroll
      for (int q = 0; q < 4; ++q) {
        const float* sf = (const float*)&sA[oo][q];
        atomicAdd(&sp[(q * 4 + 0) * B_], sf[0]);
        atomicAdd(&sp[(q * 4 + 1) * B_], sf[1]);
        atomicAdd(&sp[(q * 4 + 2) * B_], sf[2]);
        atomicAdd(&sp[(q * 4 + 3) * B_], sf[3]);
      }
    } else {
      float* sp = s_out + (size_t)blockIdx.x * M_ + (size_t)(o * P_) * B_ + lane;
      #pragma unroll
      for (int q = 0; q < 4; ++q) {
        const float* sf = (const float*)&sA[oo][q];
        sp[(q * 4 + 0) * B_] = sf[0];
        sp[(q * 4 + 1) * B_] = sf[1];
        sp[(q * 4 + 2) * B_] = sf[2];
        sp[(q * 4 + 3) * B_] = sf[3];
      }
    }
  }
}

// stage-1 reduction: P[K][M_] -> P2[16][M_]; grid 16 groups x 16 m-chunks.
__global__ __launch_bounds__(1024)
void reduce1(const float* __restrict__ spart, float* __restrict__ p2, int K) {
  const int g  = blockIdx.x >> 4;
  const int mc = blockIdx.x & 15;
  const int kpg = K >> 4;
  const int m0 = mc * 2048 + threadIdx.x;
  float a0 = 0.0f, a1 = 0.0f;
  const float* p = spart + (size_t)(g * kpg) * M_;
  for (int k = 0; k < kpg; ++k) {
    a0 += p[(size_t)k * M_ + m0];
    a1 += p[(size_t)k * M_ + m0 + 1024];
  }
  p2[(size_t)g * M_ + m0]        = a0;
  p2[(size_t)g * M_ + m0 + 1024] = a1;
}

// sum ngroups (stride M_) + squash; optionally add v_add; optionally zero a buffer.
__global__ __launch_bounds__(1024)
void v_kernel(const float* __restrict__ src, int ngroups, float scale,
              const float* __restrict__ v_add, float* __restrict__ v_out,
              float* __restrict__ zero_buf) {
  __shared__ float sq[P_ * 64];
  const int t = threadIdx.x;
  const int b = t & 63;
  const int p = t >> 6;
  const int o = blockIdx.x;
  const int q = o * P_ + p;
  float acc = 0.0f;
  for (int g = 0; g < ngroups; ++g) acc += src[(size_t)g * M_ + q * 64 + b];
  acc *= scale;
  sq[p * 64 + b] = acc * acc;
  if (zero_buf) zero_buf[blockIdx.x * 1024 + t] = 0.0f;
  __syncthreads();
  float s2 = 0.0f;
  #pragma unroll
  for (int pp = 0; pp < P_; ++pp) s2 += sq[pp * 64 + b];
  float sc = (s2 / (1.0f + s2)) / sqrtf(s2 + 1e-7f);
  float v = acc * sc;
  const int idx = b * OP_ + q;   // v layout [b][o][p]
  v_out[idx] = v + (v_add ? v_add[idx] : 0.0f);
}

extern "C" void kernel_launch(void* const* d_in, const int* in_sizes, int n_in,
                              void* d_out, int out_size, void* d_ws, size_t ws_size,
                              hipStream_t stream) {
  (void)in_sizes; (void)n_in; (void)out_size;
  const float* x = (const float*)d_in[0];
  const float* W = (const float*)d_in[1];
  float* out_v  = (float*)d_out;                       // [64][32][16]
  float* out_rw = out_v + (size_t)B_ * O_ * P_;        // [64][2048][32]
  float* vws   = (float*)d_ws;                         // v0
  float* vsum  = vws + M_;                             // v0+v1 (M_ == B_*OP_)
  float* p2    = vsum + M_;                            // 16 * M_
  float* spart = p2 + 16 * M_;                         // NBLK_ * M_

  const size_t need = (size_t)(2 * M_ + 16 * M_ + (size_t)NBLK_ * M_) * 4;

  dim3 gF(NBLK_), bF(1024), gV(O_), bV(1024), gR(256);
  if (ws_size >= need) {
    fused_pass<0, false><<<gF, bF, 0, stream>>>(x, W, nullptr, spart, nullptr);
    reduce1<<<gR, bF, 0, stream>>>(spart, p2, NBLK_);
    v_kernel<<<gV, bV, 0, stream>>>(p2, 16, 1.0f / 32.0f, nullptr, vws, nullptr);
    fused_pass<1, false><<<gF, bF, 0, stream>>>(x, W, vws, spart, nullptr);
    reduce1<<<gR, bF, 0, stream>>>(spart, p2, NBLK_);
    v_kernel<<<gV, bV, 0, stream>>>(p2, 16, 1.0f, vws, vsum, nullptr);
    fused_pass<2, false><<<gF, bF, 0, stream>>>(x, W, vsum, spart, out_rw);
    reduce1<<<gR, bF, 0, stream>>>(spart, p2, NBLK_);
    v_kernel<<<gV, bV, 0, stream>>>(p2, 16, 1.0f, nullptr, out_v, nullptr);
  } else {
    // atomic fallback for small ws
    float* sAb = p2;
    float* sBb = sAb + M_;
    hipMemsetAsync(sAb, 0, (size_t)M_ * sizeof(float), stream);
    fused_pass<0, true><<<gF, bF, 0, stream>>>(x, W, nullptr, sAb, nullptr);
    v_kernel<<<gV, bV, 0, stream>>>(sAb, 1, 1.0f / 32.0f, nullptr, vws, sBb);
    fused_pass<1, true><<<gF, bF, 0, stream>>>(x, W, vws, sBb, nullptr);
    v_kernel<<<gV, bV, 0, stream>>>(sBb, 1, 1.0f, vws, vsum, sAb);
    fused_pass<2, true><<<gF, bF, 0, stream>>>(x, W, vsum, sAb, out_rw);
    v_kernel<<<gV, bV, 0, stream>>>(sAb, 1, 1.0f, nullptr, out_v, nullptr);
  }
}

// Round 6
// 272.523 us; speedup vs baseline: 3.0887x; 3.0887x over previous
//
#include <hip/hip_runtime.h>

static constexpr int B_    = 64;
static constexpr int N_    = 2048;
static constexpr int DI_   = 8;
static constexpr int O_    = 32;
static constexpr int P_    = 16;
static constexpr int OP_   = O_ * P_;      // 512
static constexpr int M_    = OP_ * B_;     // 32768 s elements
static constexpr int CHUNK_ = 8;
static constexpr int NBLK_  = N_ / CHUNK_; // 256

// MODE 0: iter0 (uniform rw; 1/32 folded into v_kernel). No softmax, no v.
// MODE 1: merged A+B per nn: preds in regs, logits->a_lds, softmax, accumulate.
// MODE 2: MODE1 + write normalized rw to rw_out (v_in = v0+v1 by linearity).
// Register hygiene: NO address-of on private arrays, all array loops fully
// unrolled with constant indices (alloca/scratch was the R1/R4/R5 killer).
template <int MODE, bool ATOMIC>
__global__ __launch_bounds__(1024, 4)
void fused_pass(const float* __restrict__ x, const float* __restrict__ W,
                const float* __restrict__ v_in, float* __restrict__ s_out,
                float* __restrict__ rw_out) {
  __shared__ float x_lds[CHUNK_ * 8 * 65];   // [rem=(nn*8+i)][b], pad 65 (16.6 KB)
  __shared__ float a_lds[2][O_ * B_];        // double-buffered logits [o][b] (16 KB)
  const int tid  = threadIdx.x;
  const int lane = tid & 63;                 // lane == batch b
  const int wave = tid >> 6;                 // 0..15; wave owns o = 2w, 2w+1
  const int n0   = blockIdx.x * CHUNK_;

  // stage x[b][n0..n0+7][i] -> LDS (coalesced; conflict-free writes)
  #pragma unroll
  for (int k = 0; k < 4; ++k) {
    int d = k * 1024 + tid;
    int b = d >> 6, rem = d & 63;
    x_lds[rem * 65 + b] = x[b * (N_ * DI_) + n0 * DI_ + rem];
  }

  float s_r[32];
  #pragma unroll
  for (int q = 0; q < 32; ++q) s_r[q] = 0.0f;

  __syncthreads();

  #pragma unroll 1
  for (int nn = 0; nn < CHUNK_; ++nn) {
    const int n = n0 + nn;
    float xr[8];
    #pragma unroll
    for (int i = 0; i < 8; ++i) xr[i] = x_lds[(nn * 8 + i) * 65 + lane];

    float pr[2][16];
    float ao0 = 0.0f, ao1 = 0.0f;

    #pragma unroll
    for (int oo = 0; oo < 2; ++oo) {
      const int o_u = __builtin_amdgcn_readfirstlane(wave * 2 + oo);
      const float* wp = W + (size_t)(n * O_ + o_u) * (P_ * DI_);

      float4 va0, va1, va2, va3;
      if (MODE != 0) {
        const float4* vp =
            (const float4*)(v_in + (size_t)lane * OP_ + (wave * 2 + oo) * P_);
        va0 = vp[0]; va1 = vp[1]; va2 = vp[2]; va3 = vp[3];
      }

      float acc = 0.0f;
      #pragma unroll
      for (int p = 0; p < P_; ++p) {
        float pv = wp[p * 8 + 0] * xr[0];
        pv = __builtin_fmaf(wp[p * 8 + 1], xr[1], pv);
        pv = __builtin_fmaf(wp[p * 8 + 2], xr[2], pv);
        pv = __builtin_fmaf(wp[p * 8 + 3], xr[3], pv);
        pv = __builtin_fmaf(wp[p * 8 + 4], xr[4], pv);
        pv = __builtin_fmaf(wp[p * 8 + 5], xr[5], pv);
        pv = __builtin_fmaf(wp[p * 8 + 6], xr[6], pv);
        pv = __builtin_fmaf(wp[p * 8 + 7], xr[7], pv);
        if (MODE == 0) {
          s_r[oo * 16 + p] += pv;
        } else {
          pr[oo][p] = pv;
          const float vc = (p < 4)  ? ((p & 3) == 0 ? va0.x : (p & 3) == 1 ? va0.y : (p & 3) == 2 ? va0.z : va0.w)
                         : (p < 8)  ? ((p & 3) == 0 ? va1.x : (p & 3) == 1 ? va1.y : (p & 3) == 2 ? va1.z : va1.w)
                         : (p < 12) ? ((p & 3) == 0 ? va2.x : (p & 3) == 1 ? va2.y : (p & 3) == 2 ? va2.z : va2.w)
                                    : ((p & 3) == 0 ? va3.x : (p & 3) == 1 ? va3.y : (p & 3) == 2 ? va3.z : va3.w);
          acc = __builtin_fmaf(pv, vc, acc);
        }
      }
      if (MODE != 0) {
        if (oo == 0) ao0 = acc; else ao1 = acc;
        a_lds[nn & 1][(wave * 2 + oo) * B_ + lane] = acc;
      }
    }

    if (MODE != 0) {
      __syncthreads();  // a_lds[nn&1] complete

      // no-max softmax denominator (|logit| <= ~3 analytically; exp safe in fp32)
      float Z = 0.0f;
      #pragma unroll
      for (int o = 0; o < O_; ++o) Z += __expf(a_lds[nn & 1][o * B_ + lane]);
      const float rZ  = 1.0f / Z;
      const float rw0 = __expf(ao0) * rZ;
      const float rw1 = __expf(ao1) * rZ;

      #pragma unroll
      for (int p = 0; p < P_; ++p) {
        s_r[p]      = __builtin_fmaf(rw0, pr[0][p], s_r[p]);
        s_r[16 + p] = __builtin_fmaf(rw1, pr[1][p], s_r[16 + p]);
      }
      if (MODE == 2) {
        float2 t; t.x = rw0; t.y = rw1;
        *(float2*)(rw_out + ((size_t)lane * N_ + n) * O_ + wave * 2) = t;
      }
    }
  }

  // epilogue: block partial (layout [blk][q=o*16+p][b]) or atomic fallback
  if (ATOMIC) {
    #pragma unroll
    for (int oo = 0; oo < 2; ++oo) {
      float* sp = s_out + (size_t)((wave * 2 + oo) * P_) * B_ + lane;
      #pragma unroll
      for (int p = 0; p < P_; ++p) atomicAdd(&sp[p * B_], s_r[oo * 16 + p]);
    }
  } else {
    #pragma unroll
    for (int oo = 0; oo < 2; ++oo) {
      float* sp = s_out + (size_t)blockIdx.x * M_ +
                  (size_t)((wave * 2 + oo) * P_) * B_ + lane;
      #pragma unroll
      for (int p = 0; p < P_; ++p) sp[p * B_] = s_r[oo * 16 + p];
    }
  }
}

// stage-1 reduction: P[K][M_] -> P2[16][M_]; grid 16 groups x 16 m-chunks.
__global__ __launch_bounds__(1024)
void reduce1(const float* __restrict__ spart, float* __restrict__ p2, int K) {
  const int g  = blockIdx.x >> 4;
  const int mc = blockIdx.x & 15;
  const int kpg = K >> 4;
  const int m0 = mc * 2048 + threadIdx.x;
  float a0 = 0.0f, a1 = 0.0f;
  const float* p = spart + (size_t)(g * kpg) * M_;
  for (int k = 0; k < kpg; ++k) {
    a0 += p[(size_t)k * M_ + m0];
    a1 += p[(size_t)k * M_ + m0 + 1024];
  }
  p2[(size_t)g * M_ + m0]        = a0;
  p2[(size_t)g * M_ + m0 + 1024] = a1;
}

// sum ngroups (stride M_) + squash; optionally add v_add; optionally zero a buffer.
__global__ __launch_bounds__(1024)
void v_kernel(const float* __restrict__ src, int ngroups, float scale,
              const float* __restrict__ v_add, float* __restrict__ v_out,
              float* __restrict__ zero_buf) {
  __shared__ float sq[P_ * 64];
  const int t = threadIdx.x;
  const int b = t & 63;
  const int p = t >> 6;
  const int o = blockIdx.x;
  const int q = o * P_ + p;
  float acc = 0.0f;
  for (int g = 0; g < ngroups; ++g) acc += src[(size_t)g * M_ + q * 64 + b];
  acc *= scale;
  sq[p * 64 + b] = acc * acc;
  if (zero_buf) zero_buf[blockIdx.x * 1024 + t] = 0.0f;
  __syncthreads();
  float s2 = 0.0f;
  #pragma unroll
  for (int pp = 0; pp < P_; ++pp) s2 += sq[pp * 64 + b];
  float sc = (s2 / (1.0f + s2)) / sqrtf(s2 + 1e-7f);
  float v = acc * sc;
  const int idx = b * OP_ + q;   // v layout [b][o][p]
  v_out[idx] = v + (v_add ? v_add[idx] : 0.0f);
}

extern "C" void kernel_launch(void* const* d_in, const int* in_sizes, int n_in,
                              void* d_out, int out_size, void* d_ws, size_t ws_size,
                              hipStream_t stream) {
  (void)in_sizes; (void)n_in; (void)out_size;
  const float* x = (const float*)d_in[0];
  const float* W = (const float*)d_in[1];
  float* out_v  = (float*)d_out;                       // [64][32][16]
  float* out_rw = out_v + (size_t)B_ * O_ * P_;        // [64][2048][32]
  float* vws   = (float*)d_ws;                         // v0
  float* vsum  = vws + M_;                             // v0+v1
  float* p2    = vsum + M_;                            // 16 * M_
  float* spart = p2 + 16 * M_;                         // NBLK_ * M_

  const size_t need = (size_t)(2 * M_ + 16 * M_ + (size_t)NBLK_ * M_) * 4;

  dim3 gF(NBLK_), bF(1024), gV(O_), bV(1024), gR(256);
  if (ws_size >= need) {
    fused_pass<0, false><<<gF, bF, 0, stream>>>(x, W, nullptr, spart, nullptr);
    reduce1<<<gR, bF, 0, stream>>>(spart, p2, NBLK_);
    v_kernel<<<gV, bV, 0, stream>>>(p2, 16, 1.0f / 32.0f, nullptr, vws, nullptr);
    fused_pass<1, false><<<gF, bF, 0, stream>>>(x, W, vws, spart, nullptr);
    reduce1<<<gR, bF, 0, stream>>>(spart, p2, NBLK_);
    v_kernel<<<gV, bV, 0, stream>>>(p2, 16, 1.0f, vws, vsum, nullptr);
    fused_pass<2, false><<<gF, bF, 0, stream>>>(x, W, vsum, spart, out_rw);
    reduce1<<<gR, bF, 0, stream>>>(spart, p2, NBLK_);
    v_kernel<<<gV, bV, 0, stream>>>(p2, 16, 1.0f, nullptr, out_v, nullptr);
  } else {
    // atomic fallback for small ws
    float* sAb = p2;
    float* sBb = sAb + M_;
    hipMemsetAsync(sAb, 0, (size_t)M_ * sizeof(float), stream);
    fused_pass<0, true><<<gF, bF, 0, stream>>>(x, W, nullptr, sAb, nullptr);
    v_kernel<<<gV, bV, 0, stream>>>(sAb, 1, 1.0f / 32.0f, nullptr, vws, sBb);
    fused_pass<1, true><<<gF, bF, 0, stream>>>(x, W, vws, sBb, nullptr);
    v_kernel<<<gV, bV, 0, stream>>>(sBb, 1, 1.0f, vws, vsum, sAb);
    fused_pass<2, true><<<gF, bF, 0, stream>>>(x, W, vsum, sAb, out_rw);
    v_kernel<<<gV, bV, 0, stream>>>(sAb, 1, 1.0f, nullptr, out_v, nullptr);
  }
}